// Round 7
// baseline (189.075 us; speedup 1.0000x reference)
//
#include <hip/hip_runtime.h>

#define NTOT 4096
#define CH 256
#define SCALE 0.0390625f   // 1/(256*0.1)
#define LAM 0.001f

typedef unsigned short u16;
typedef __attribute__((ext_vector_type(8))) short short8;   // 8 bf16 (4 VGPRs)
typedef __attribute__((ext_vector_type(4))) float floatx4;  // MFMA acc

__device__ __forceinline__ float wave_sum64(float v) {
  #pragma unroll
  for (int o = 32; o; o >>= 1) v += __shfl_down(v, o, 64);
  return v;
}
__device__ __forceinline__ u16 f2bf(float f) {  // round-to-nearest-even
  unsigned u = __float_as_uint(f);
  u += 0x7fffu + ((u >> 16) & 1u);
  return (u16)(u >> 16);
}
__device__ __forceinline__ float bf2f(u16 h) {
  return __uint_as_float(((unsigned)h) << 16);
}
__device__ __forceinline__ void gload_lds(const u16* g, void* l) {
  __builtin_amdgcn_global_load_lds((const __attribute__((address_space(1))) void*)g,
                                   (__attribute__((address_space(3))) void*)l, 16, 0, 0);
}
__device__ __forceinline__ void mm4x4(const short8 (&av)[4], const short8 (&bv)[4],
                                      floatx4 (&acc)[4][4]) {
  #pragma unroll
  for (int m = 0; m < 4; ++m)
    #pragma unroll
    for (int n = 0; n < 4; ++n)
      acc[m][n] = __builtin_amdgcn_mfma_f32_16x16x32_bf16(av[m], bv[n], acc[m][n], 0, 0, 0);
}

// f32 -> bf16 for both inputs + row norms of the ROUNDED values (one wave/row).
__global__ __launch_bounds__(64) void cvt_norm_k(const float* __restrict__ a,
                                                 const float* __restrict__ b,
                                                 u16* __restrict__ ab, u16* __restrict__ bb,
                                                 float* __restrict__ na, float* __restrict__ nb) {
  int row = blockIdx.x;
  const float* src; u16* dst; float* nd;
  if (row < NTOT) { src = a; dst = ab; nd = na; }
  else { row -= NTOT; src = b; dst = bb; nd = nb; }
  const float4 v = *reinterpret_cast<const float4*>(src + (size_t)row * CH + threadIdx.x * 4);
  const u16 h0 = f2bf(v.x), h1 = f2bf(v.y), h2 = f2bf(v.z), h3 = f2bf(v.w);
  uint2 st;
  st.x = (unsigned)h0 | ((unsigned)h1 << 16);
  st.y = (unsigned)h2 | ((unsigned)h3 << 16);
  *reinterpret_cast<uint2*>(dst + (size_t)row * CH + threadIdx.x * 4) = st;
  const float f0 = bf2f(h0), f1 = bf2f(h1), f2 = bf2f(h2), f3 = bf2f(h3);
  float s = f0 * f0 + f1 * f1 + f2 * f2 + f3 * f3;
  s = wave_sum64(s);
  if (threadIdx.x == 0) nd[row] = s;
}

// [4096][256] -> [256][4096] bf16 transpose for both inputs (z selects a/b)
__global__ __launch_bounds__(256) void transpose2_k(const u16* __restrict__ ab,
                                                    const u16* __restrict__ bb,
                                                    u16* __restrict__ at, u16* __restrict__ bt) {
  const u16* __restrict__ src = blockIdx.z ? bb : ab;
  u16* __restrict__ dst = blockIdx.z ? bt : at;
  __shared__ u16 t[32][33];
  const int bx = blockIdx.x * 32, by = blockIdx.y * 32;
  const int lx = threadIdx.x & 31, ly = threadIdx.x >> 5;
  #pragma unroll
  for (int i = 0; i < 32; i += 8)
    t[ly + i][lx] = src[(size_t)(by + ly + i) * CH + bx + lx];
  __syncthreads();
  #pragma unroll
  for (int i = 0; i < 32; i += 8)
    dst[(size_t)(bx + ly + i) * NTOT + by + lx] = t[lx][ly + i];
}

// ---------------------------------------------------------------------------
// Phase-1 GEMM fused with exp: E = bf16(exp((2*X.Y^T - ny)*SCALE)), per-row
// partial sums dnp. Both dirs via blockIdx.z. SINGLE-buffered 32KB LDS
// (m97 stage/sync/compute/sync) -> 4 blocks/CU for TLP latency hiding.
// XOR swizzle retained (conflicts stay 0).
__global__ __launch_bounds__(256, 4) void gemm_exp_k(const u16* __restrict__ abf,
                                                     const u16* __restrict__ bbf,
                                                     const float* __restrict__ na,
                                                     const float* __restrict__ nb,
                                                     u16* __restrict__ E,
                                                     float* __restrict__ dnp) {
  const int dir = blockIdx.z;
  const u16* __restrict__ A = dir ? bbf : abf;
  const u16* __restrict__ B = dir ? abf : bbf;
  const float* __restrict__ ny = dir ? na : nb;
  E += (size_t)dir * NTOT * NTOT;
  dnp += (size_t)dir * NTOT * 64;

  __shared__ u16 As[128][64];
  __shared__ u16 Bs[128][64];
  const int tid = threadIdx.x, wid = tid >> 6, lane = tid & 63;
  const int bn = blockIdx.x * 128, bm = blockIdx.y * 128;
  const int wr = (wid >> 1) * 64, wc = (wid & 1) * 64;
  const int lr = lane & 15;

  floatx4 acc[4][4] = {};
  #pragma unroll
  for (int t = 0; t < 4; ++t) {
    if (t) __syncthreads();              // prev compute done reading LDS
    const int k0 = t * 64;
    #pragma unroll
    for (int i = 0; i < 4; ++i) {
      const int lb = (wid + 4 * i) * 1024;          // wave-uniform LDS byte base
      const int db = lb + lane * 16;                // lane's linear dest byte
      const int r = db >> 7;                        // dest row (128 B rows)
      const int cb = (db & 127) ^ ((r & 7) << 4);   // inverse-swizzled source col
      gload_lds(A + (size_t)(bm + r) * CH + k0 + (cb >> 1), (char*)&As[0][0] + lb);
      gload_lds(B + (size_t)(bn + r) * CH + k0 + (cb >> 1), (char*)&Bs[0][0] + lb);
    }
    __syncthreads();                     // drains vmcnt(0) before barrier
    const char* Ab = (const char*)&As[0][0];
    const char* Bb = (const char*)&Bs[0][0];
    #pragma unroll
    for (int ks = 0; ks < 2; ++ks) {
      const int ob = ks * 64 + (lane >> 4) * 16;    // desired byte col in row
      short8 af[4], bfr[4];
      #pragma unroll
      for (int m = 0; m < 4; ++m) {
        const int row = wr + m * 16 + lr;
        af[m] = *reinterpret_cast<const short8*>(Ab + row * 128 + (ob ^ ((row & 7) << 4)));
      }
      #pragma unroll
      for (int n = 0; n < 4; ++n) {
        const int row = wc + n * 16 + lr;
        bfr[n] = *reinterpret_cast<const short8*>(Bb + row * 128 + (ob ^ ((row & 7) << 4)));
      }
      mm4x4(af, bfr, acc);
    }
  }
  // epilogue: w = exp(logit), write bf16 E, accumulate per-row sums
  float nyv[4];
  #pragma unroll
  for (int n = 0; n < 4; ++n) nyv[n] = ny[bn + wc + n * 16 + lr];
  float rowsum[4][4] = {};
  #pragma unroll
  for (int m = 0; m < 4; ++m) {
    const int rowb = bm + wr + m * 16 + (lane >> 4) * 4;
    #pragma unroll
    for (int n = 0; n < 4; ++n) {
      const int col = bn + wc + n * 16 + lr;
      #pragma unroll
      for (int r = 0; r < 4; ++r) {
        const float w = __expf((2.f * acc[m][n][r] - nyv[n]) * SCALE);
        E[(size_t)(rowb + r) * NTOT + col] = f2bf(w);
        rowsum[m][r] += w;
      }
    }
  }
  #pragma unroll
  for (int m = 0; m < 4; ++m) {
    const int rowb = bm + wr + m * 16 + (lane >> 4) * 4;
    #pragma unroll
    for (int r = 0; r < 4; ++r) {
      float s = rowsum[m][r];
      #pragma unroll
      for (int o = 1; o < 16; o <<= 1) s += __shfl_xor(s, o, 64);
      if (lr == 0) dnp[(size_t)(rowb + r) * 64 + blockIdx.x * 2 + (wid & 1)] = s;
    }
  }
}

// ---------------------------------------------------------------------------
// Qp = E . Yt^T, split-K 8, both dirs. z = dir*8 + kz. Single-buffered 32KB,
// 4 blocks/CU, XOR swizzle.
__global__ __launch_bounds__(256, 4) void gemm_qp_k(const u16* __restrict__ E,
                                                    const u16* __restrict__ att,
                                                    const u16* __restrict__ btt,
                                                    float* __restrict__ Qp) {
  const int dir = blockIdx.z >> 3, kz = blockIdx.z & 7;
  const u16* __restrict__ A = E + (size_t)dir * NTOT * NTOT;
  const u16* __restrict__ B = dir ? att : btt;
  float* __restrict__ C = Qp + (size_t)dir * 8 * NTOT * CH + (size_t)kz * NTOT * CH;
  const int k0base = kz * (NTOT / 8);

  __shared__ u16 As[128][64];
  __shared__ u16 Bs[128][64];
  const int tid = threadIdx.x, wid = tid >> 6, lane = tid & 63;
  const int bn = blockIdx.x * 128, bm = blockIdx.y * 128;
  const int wr = (wid >> 1) * 64, wc = (wid & 1) * 64;
  const int lr = lane & 15;

  floatx4 acc[4][4] = {};
  for (int t = 0; t < 8; ++t) {
    if (t) __syncthreads();
    const int k0 = k0base + t * 64;
    #pragma unroll
    for (int i = 0; i < 4; ++i) {
      const int lb = (wid + 4 * i) * 1024;
      const int db = lb + lane * 16;
      const int r = db >> 7;
      const int cb = (db & 127) ^ ((r & 7) << 4);
      gload_lds(A + (size_t)(bm + r) * NTOT + k0 + (cb >> 1), (char*)&As[0][0] + lb);
      gload_lds(B + (size_t)(bn + r) * NTOT + k0 + (cb >> 1), (char*)&Bs[0][0] + lb);
    }
    __syncthreads();
    const char* Ab = (const char*)&As[0][0];
    const char* Bb = (const char*)&Bs[0][0];
    #pragma unroll
    for (int ks = 0; ks < 2; ++ks) {
      const int ob = ks * 64 + (lane >> 4) * 16;
      short8 af[4], bfr[4];
      #pragma unroll
      for (int m = 0; m < 4; ++m) {
        const int row = wr + m * 16 + lr;
        af[m] = *reinterpret_cast<const short8*>(Ab + row * 128 + (ob ^ ((row & 7) << 4)));
      }
      #pragma unroll
      for (int n = 0; n < 4; ++n) {
        const int row = wc + n * 16 + lr;
        bfr[n] = *reinterpret_cast<const short8*>(Bb + row * 128 + (ob ^ ((row & 7) << 4)));
      }
      mm4x4(af, bfr, acc);
    }
  }
  #pragma unroll
  for (int m = 0; m < 4; ++m) {
    const int row = bm + wr + m * 16 + (lane >> 4) * 4;
    #pragma unroll
    for (int n = 0; n < 4; ++n) {
      const int col = bn + wc + n * 16 + lr;
      #pragma unroll
      for (int r = 0; r < 4; ++r)
        C[(size_t)(row + r) * CH + col] = acc[m][n][r];
    }
  }
}

// Q = (sum of 8 split-K partials) / dn -> bf16. Block per row; both dirs via z.
__global__ __launch_bounds__(256) void reduce_q_k(const float* __restrict__ Qp,
                                                  const float* __restrict__ dnp,
                                                  u16* __restrict__ Qb) {
  const int dir = blockIdx.z;
  Qp += (size_t)dir * 8 * NTOT * CH;
  dnp += (size_t)dir * NTOT * 64;
  Qb += (size_t)dir * NTOT * CH;
  const int row = blockIdx.x, tid = threadIdx.x;
  __shared__ float sdn;
  if (tid < 64) {
    float s = dnp[(size_t)row * 64 + tid];
    s = wave_sum64(s);
    if (tid == 0) sdn = 1.0f / s;
  }
  __syncthreads();
  const float rdn = sdn;
  const size_t o = (size_t)row * CH + tid;
  const size_t st = (size_t)NTOT * CH;
  float q = 0.f;
  #pragma unroll
  for (int p = 0; p < 8; ++p) q += Qp[o + p * st];
  Qb[o] = f2bf(q * rdn);
}

// ---------------------------------------------------------------------------
// Phase-2 flash: T-tile = Qb . X^T (never materialized); w = exp((2T-nx)*SCALE);
// s0, s1 = sum w*(idx-c), s2 = sum w*(idx-c)^2 per row. Both dirs.
// 2 j-tiles x 4 K-steps, single-buffered 32KB, 4 blocks/CU, XOR swizzle.
__global__ __launch_bounds__(256, 4) void flash_stats_k(const u16* __restrict__ Qball,
                                                        const u16* __restrict__ abf,
                                                        const u16* __restrict__ bbf,
                                                        const float* __restrict__ na,
                                                        const float* __restrict__ nb,
                                                        const float* __restrict__ idxa,
                                                        const float* __restrict__ idxb,
                                                        float4* __restrict__ statsp) {
  const int dir = blockIdx.z;
  const u16* __restrict__ Qb = Qball + (size_t)dir * NTOT * CH;
  const u16* __restrict__ X = dir ? bbf : abf;
  const float* __restrict__ nx = dir ? nb : na;
  const float* __restrict__ idx = dir ? idxb : idxa;
  statsp += (size_t)dir * NTOT * 32;

  __shared__ u16 As[128][64];
  __shared__ u16 Bs[128][64];
  const int tid = threadIdx.x, wid = tid >> 6, lane = tid & 63;
  const int bm = blockIdx.y * 128;
  const int jbase = blockIdx.x * 256;
  const int wr = (wid >> 1) * 64, wc = (wid & 1) * 64;
  const int lr = lane & 15;

  float cen[4][4];
  #pragma unroll
  for (int m = 0; m < 4; ++m) {
    const int rowb = bm + wr + m * 16 + (lane >> 4) * 4;
    #pragma unroll
    for (int r = 0; r < 4; ++r) cen[m][r] = idx[rowb + r];
  }
  float s0[4][4] = {}, s1[4][4] = {}, s2[4][4] = {};
  floatx4 acc[4][4] = {};

  #pragma unroll
  for (int t = 0; t < 8; ++t) {
    if (t) __syncthreads();
    const int k0 = (t & 3) * 64;
    const int bn = jbase + (t >> 2) * 128;
    #pragma unroll
    for (int i = 0; i < 4; ++i) {
      const int lb = (wid + 4 * i) * 1024;
      const int db = lb + lane * 16;
      const int r = db >> 7;
      const int cb = (db & 127) ^ ((r & 7) << 4);
      gload_lds(Qb + (size_t)(bm + r) * CH + k0 + (cb >> 1), (char*)&As[0][0] + lb);
      gload_lds(X + (size_t)(bn + r) * CH + k0 + (cb >> 1), (char*)&Bs[0][0] + lb);
    }
    __syncthreads();
    const char* Ab = (const char*)&As[0][0];
    const char* Bb = (const char*)&Bs[0][0];
    #pragma unroll
    for (int ks = 0; ks < 2; ++ks) {
      const int ob = ks * 64 + (lane >> 4) * 16;
      short8 af[4], bfr[4];
      #pragma unroll
      for (int m = 0; m < 4; ++m) {
        const int row = wr + m * 16 + lr;
        af[m] = *reinterpret_cast<const short8*>(Ab + row * 128 + (ob ^ ((row & 7) << 4)));
      }
      #pragma unroll
      for (int n = 0; n < 4; ++n) {
        const int row = wc + n * 16 + lr;
        bfr[n] = *reinterpret_cast<const short8*>(Bb + row * 128 + (ob ^ ((row & 7) << 4)));
      }
      mm4x4(af, bfr, acc);
    }
    if ((t & 3) == 3) {  // end of a j-tile: fold stats, reset acc
      const int bn2 = jbase + (t >> 2) * 128;
      #pragma unroll
      for (int n = 0; n < 4; ++n) {
        const int col = bn2 + wc + n * 16 + lr;
        const float nxv = nx[col];
        const float iv = idx[col];
        #pragma unroll
        for (int m = 0; m < 4; ++m) {
          #pragma unroll
          for (int r = 0; r < 4; ++r) {
            const float w = __expf((2.f * acc[m][n][r] - nxv) * SCALE);
            const float d = iv - cen[m][r];
            s0[m][r] += w;
            s1[m][r] += w * d;
            s2[m][r] += w * d * d;
            acc[m][n][r] = 0.f;
          }
        }
      }
    }
  }
  #pragma unroll
  for (int m = 0; m < 4; ++m) {
    const int rowb = bm + wr + m * 16 + (lane >> 4) * 4;
    #pragma unroll
    for (int r = 0; r < 4; ++r) {
      float a = s0[m][r], b = s1[m][r], c = s2[m][r];
      #pragma unroll
      for (int o = 1; o < 16; o <<= 1) {
        a += __shfl_xor(a, o, 64);
        b += __shfl_xor(b, o, 64);
        c += __shfl_xor(c, o, 64);
      }
      if (lr == 0)
        statsp[(size_t)(rowb + r) * 32 + blockIdx.x * 2 + (wid & 1)] = make_float4(a, b, c, 0.f);
    }
  }
}

// per-row: combine 32 partials -> loss term. mu = S1/S0; var = S2/S0 - mu^2.
__global__ __launch_bounds__(256) void stats_combine_k(const float4* __restrict__ statsp,
                                                       float* __restrict__ terms) {
  const int row = blockIdx.x * 256 + threadIdx.x;   // 0..2*NTOT-1
  float S0 = 0.f, S1 = 0.f, S2 = 0.f;
  #pragma unroll
  for (int p = 0; p < 32; ++p) {
    const float4 v = statsp[(size_t)row * 32 + p];
    S0 += v.x; S1 += v.y; S2 += v.z;
  }
  const float mu = S1 / S0;
  const float var = S2 / S0 - mu * mu;
  terms[row] = mu * mu / var + LAM * logf(var);
}

__global__ __launch_bounds__(256) void final_reduce_k(const float* __restrict__ terms,
                                                      float* __restrict__ out) {
  float s = 0.f;
  for (int i = threadIdx.x; i < 2 * NTOT; i += 256) s += terms[i];
  __shared__ float red[4];
  s = wave_sum64(s);
  if ((threadIdx.x & 63) == 0) red[threadIdx.x >> 6] = s;
  __syncthreads();
  if (threadIdx.x == 0) out[0] = (red[0] + red[1] + red[2] + red[3]) * (1.0f / (2.0f * NTOT));
}

extern "C" void kernel_launch(void* const* d_in, const int* in_sizes, int n_in,
                              void* d_out, int out_size, void* d_ws, size_t ws_size,
                              hipStream_t stream) {
  const float* a    = (const float*)d_in[0];
  const float* b    = (const float*)d_in[1];
  const float* idxa = (const float*)d_in[2];
  const float* idxb = (const float*)d_in[3];
  float* out = (float*)d_out;
  char* ws = (char*)d_ws;

  size_t off = 0;
  u16*    E    = (u16*)(ws + off);    off += 2 * (size_t)NTOT * NTOT * 2;   // 64 MB
  float*  Qp   = (float*)(ws + off);  off += 2 * 8 * (size_t)NTOT * CH * 4; // 64 MB
  u16*    Qb   = (u16*)(ws + off);    off += 2 * (size_t)NTOT * CH * 2;     // 4 MB
  u16*    abf  = (u16*)(ws + off);    off += (size_t)NTOT * CH * 2;
  u16*    bbf  = (u16*)(ws + off);    off += (size_t)NTOT * CH * 2;
  u16*    att  = (u16*)(ws + off);    off += (size_t)NTOT * CH * 2;
  u16*    btt  = (u16*)(ws + off);    off += (size_t)NTOT * CH * 2;
  float*  na   = (float*)(ws + off);  off += (size_t)NTOT * 4;
  float*  nb   = (float*)(ws + off);  off += (size_t)NTOT * 4;
  float*  dnp  = (float*)(ws + off);  off += 2 * (size_t)NTOT * 64 * 4;     // 2 MB
  float4* stp  = (float4*)(ws + off); off += 2 * (size_t)NTOT * 32 * 16;    // 4 MB
  float*  terms = (float*)(ws + off);

  cvt_norm_k<<<2 * NTOT, 64, 0, stream>>>(a, b, abf, bbf, na, nb);
  transpose2_k<<<dim3(CH / 32, NTOT / 32, 2), 256, 0, stream>>>(abf, bbf, att, btt);
  gemm_exp_k<<<dim3(NTOT / 128, NTOT / 128, 2), 256, 0, stream>>>(abf, bbf, na, nb, E, dnp);
  gemm_qp_k<<<dim3(CH / 128, NTOT / 128, 16), 256, 0, stream>>>(E, att, btt, Qp);
  reduce_q_k<<<dim3(NTOT, 1, 2), 256, 0, stream>>>(Qp, dnp, Qb);
  flash_stats_k<<<dim3(16, NTOT / 128, 2), 256, 0, stream>>>(Qb, abf, bbf, na, nb,
                                                             idxa, idxb, stp);
  stats_combine_k<<<2 * NTOT / 256, 256, 0, stream>>>(stp, terms);
  final_reduce_k<<<1, 256, 0, stream>>>(terms, out);
}

// Round 8
// 152.876 us; speedup vs baseline: 1.2368x; 1.2368x over previous
//
#include <hip/hip_runtime.h>

#define NTOT 4096
#define CH 256
#define SCALE 0.0390625f   // 1/(256*0.1)
#define LAM 0.001f

typedef unsigned short u16;
typedef __attribute__((ext_vector_type(8))) short short8;   // 8 bf16 (4 VGPRs)
typedef __attribute__((ext_vector_type(4))) float floatx4;  // MFMA acc

__device__ __forceinline__ float wave_sum64(float v) {
  #pragma unroll
  for (int o = 32; o; o >>= 1) v += __shfl_down(v, o, 64);
  return v;
}
__device__ __forceinline__ u16 f2bf(float f) {  // round-to-nearest-even
  unsigned u = __float_as_uint(f);
  u += 0x7fffu + ((u >> 16) & 1u);
  return (u16)(u >> 16);
}
__device__ __forceinline__ float bf2f(u16 h) {
  return __uint_as_float(((unsigned)h) << 16);
}
__device__ __forceinline__ void gload_lds(const u16* g, void* l) {
  __builtin_amdgcn_global_load_lds((const __attribute__((address_space(1))) void*)g,
                                   (__attribute__((address_space(3))) void*)l, 16, 0, 0);
}
__device__ __forceinline__ void mm4x4(const short8 (&av)[4], const short8 (&bv)[4],
                                      floatx4 (&acc)[4][4]) {
  #pragma unroll
  for (int m = 0; m < 4; ++m)
    #pragma unroll
    for (int n = 0; n < 4; ++n)
      acc[m][n] = __builtin_amdgcn_mfma_f32_16x16x32_bf16(av[m], bv[n], acc[m][n], 0, 0, 0);
}
// BK=32 tiles: rows are 64 B. Swizzle byte ^= ((row>>1)&3)<<4 -> 16 lanes spread
// over 8 bank-slot groups = 2-way aliasing (free). Applied on SOURCE + READ.
__device__ __forceinline__ int swz64(int row) { return ((row >> 1) & 3) << 4; }

// f32 -> bf16 for both inputs + row norms of the ROUNDED values (one wave/row).
__global__ __launch_bounds__(64) void cvt_norm_k(const float* __restrict__ a,
                                                 const float* __restrict__ b,
                                                 u16* __restrict__ ab, u16* __restrict__ bb,
                                                 float* __restrict__ na, float* __restrict__ nb) {
  int row = blockIdx.x;
  const float* src; u16* dst; float* nd;
  if (row < NTOT) { src = a; dst = ab; nd = na; }
  else { row -= NTOT; src = b; dst = bb; nd = nb; }
  const float4 v = *reinterpret_cast<const float4*>(src + (size_t)row * CH + threadIdx.x * 4);
  const u16 h0 = f2bf(v.x), h1 = f2bf(v.y), h2 = f2bf(v.z), h3 = f2bf(v.w);
  uint2 st;
  st.x = (unsigned)h0 | ((unsigned)h1 << 16);
  st.y = (unsigned)h2 | ((unsigned)h3 << 16);
  *reinterpret_cast<uint2*>(dst + (size_t)row * CH + threadIdx.x * 4) = st;
  const float f0 = bf2f(h0), f1 = bf2f(h1), f2 = bf2f(h2), f3 = bf2f(h3);
  float s = f0 * f0 + f1 * f1 + f2 * f2 + f3 * f3;
  s = wave_sum64(s);
  if (threadIdx.x == 0) nd[row] = s;
}

// [4096][256] -> [256][4096] bf16 transpose for both inputs (z selects a/b)
__global__ __launch_bounds__(256) void transpose2_k(const u16* __restrict__ ab,
                                                    const u16* __restrict__ bb,
                                                    u16* __restrict__ at, u16* __restrict__ bt) {
  const u16* __restrict__ src = blockIdx.z ? bb : ab;
  u16* __restrict__ dst = blockIdx.z ? bt : at;
  __shared__ u16 t[32][33];
  const int bx = blockIdx.x * 32, by = blockIdx.y * 32;
  const int lx = threadIdx.x & 31, ly = threadIdx.x >> 5;
  #pragma unroll
  for (int i = 0; i < 32; i += 8)
    t[ly + i][lx] = src[(size_t)(by + ly + i) * CH + bx + lx];
  __syncthreads();
  #pragma unroll
  for (int i = 0; i < 32; i += 8)
    dst[(size_t)(bx + ly + i) * NTOT + by + lx] = t[lx][ly + i];
}

// ---------------------------------------------------------------------------
// Phase-1 GEMM fused with exp: E = bf16(exp((2*X.Y^T - ny)*SCALE)), per-row
// partial sums dnp. Both dirs via blockIdx.z. BK=32 DOUBLE-buffered (32 KB
// total LDS -> 4 blocks/CU, dbuf overlap preserved). Swizzled staging.
__global__ __launch_bounds__(256, 4) void gemm_exp_k(const u16* __restrict__ abf,
                                                     const u16* __restrict__ bbf,
                                                     const float* __restrict__ na,
                                                     const float* __restrict__ nb,
                                                     u16* __restrict__ E,
                                                     float* __restrict__ dnp) {
  const int dir = blockIdx.z;
  const u16* __restrict__ A = dir ? bbf : abf;
  const u16* __restrict__ B = dir ? abf : bbf;
  const float* __restrict__ ny = dir ? na : nb;
  E += (size_t)dir * NTOT * NTOT;
  dnp += (size_t)dir * NTOT * 64;

  __shared__ u16 As[2][128][32];
  __shared__ u16 Bs[2][128][32];
  const int tid = threadIdx.x, wid = tid >> 6, lane = tid & 63;
  const int bn = blockIdx.x * 128, bm = blockIdx.y * 128;
  const int wr = (wid >> 1) * 64, wc = (wid & 1) * 64;
  const int lr = lane & 15, g = lane >> 4;

  auto stage = [&](int t, int bi) {
    const int k0 = t * 32;
    #pragma unroll
    for (int i = 0; i < 2; ++i) {
      const int lb = (wid + 4 * i) * 1024;          // wave-uniform LDS byte base
      const int db = lb + lane * 16;                // lane's linear dest byte
      const int r = db >> 6;                        // dest row (64 B rows)
      const int cb = (db & 63) ^ swz64(r);          // inverse-swizzled source col
      gload_lds(A + (size_t)(bm + r) * CH + k0 + (cb >> 1), (char*)&As[bi][0][0] + lb);
      gload_lds(B + (size_t)(bn + r) * CH + k0 + (cb >> 1), (char*)&Bs[bi][0][0] + lb);
    }
  };

  floatx4 acc[4][4] = {};
  stage(0, 0);
  asm volatile("s_waitcnt vmcnt(0)" ::: "memory");
  __builtin_amdgcn_s_barrier();
  #pragma unroll
  for (int t = 0; t < 8; ++t) {
    if (t < 7) stage(t + 1, (t + 1) & 1);
    const int bi = t & 1;
    const char* Ab = (const char*)&As[bi][0][0];
    const char* Bb = (const char*)&Bs[bi][0][0];
    short8 af[4], bfr[4];
    #pragma unroll
    for (int m = 0; m < 4; ++m) {
      const int row = wr + m * 16 + lr;
      af[m] = *reinterpret_cast<const short8*>(Ab + row * 64 + ((g * 16) ^ swz64(row)));
    }
    #pragma unroll
    for (int n = 0; n < 4; ++n) {
      const int row = wc + n * 16 + lr;
      bfr[n] = *reinterpret_cast<const short8*>(Bb + row * 64 + ((g * 16) ^ swz64(row)));
    }
    mm4x4(af, bfr, acc);
    if (t < 7) {
      asm volatile("s_waitcnt vmcnt(0)" ::: "memory");
      __builtin_amdgcn_s_barrier();
    }
  }
  // epilogue: w = exp(logit), write bf16 E, accumulate per-row sums
  float nyv[4];
  #pragma unroll
  for (int n = 0; n < 4; ++n) nyv[n] = ny[bn + wc + n * 16 + lr];
  float rowsum[4][4] = {};
  #pragma unroll
  for (int m = 0; m < 4; ++m) {
    const int rowb = bm + wr + m * 16 + g * 4;
    #pragma unroll
    for (int n = 0; n < 4; ++n) {
      const int col = bn + wc + n * 16 + lr;
      #pragma unroll
      for (int r = 0; r < 4; ++r) {
        const float w = __expf((2.f * acc[m][n][r] - nyv[n]) * SCALE);
        E[(size_t)(rowb + r) * NTOT + col] = f2bf(w);
        rowsum[m][r] += w;
      }
    }
  }
  #pragma unroll
  for (int m = 0; m < 4; ++m) {
    const int rowb = bm + wr + m * 16 + g * 4;
    #pragma unroll
    for (int r = 0; r < 4; ++r) {
      float s = rowsum[m][r];
      #pragma unroll
      for (int o = 1; o < 16; o <<= 1) s += __shfl_xor(s, o, 64);
      if (lr == 0) dnp[(size_t)(rowb + r) * 64 + blockIdx.x * 2 + (wid & 1)] = s;
    }
  }
}

// ---------------------------------------------------------------------------
// Qp = E . Yt^T, split-K 4, both dirs. z = dir*4 + kz. BK=32 double-buffered,
// 4 blocks/CU, swizzled staging.
__global__ __launch_bounds__(256, 4) void gemm_qp_k(const u16* __restrict__ E,
                                                    const u16* __restrict__ att,
                                                    const u16* __restrict__ btt,
                                                    float* __restrict__ Qp) {
  const int dir = blockIdx.z >> 2, kz = blockIdx.z & 3;
  const u16* __restrict__ A = E + (size_t)dir * NTOT * NTOT;
  const u16* __restrict__ B = dir ? att : btt;
  float* __restrict__ C = Qp + (size_t)dir * 4 * NTOT * CH + (size_t)kz * NTOT * CH;
  const int k0base = kz * (NTOT / 4);

  __shared__ u16 As[2][128][32];
  __shared__ u16 Bs[2][128][32];
  const int tid = threadIdx.x, wid = tid >> 6, lane = tid & 63;
  const int bn = blockIdx.x * 128, bm = blockIdx.y * 128;
  const int wr = (wid >> 1) * 64, wc = (wid & 1) * 64;
  const int lr = lane & 15, g = lane >> 4;

  auto stage = [&](int t, int bi) {
    const int k0 = k0base + t * 32;
    #pragma unroll
    for (int i = 0; i < 2; ++i) {
      const int lb = (wid + 4 * i) * 1024;
      const int db = lb + lane * 16;
      const int r = db >> 6;
      const int cb = (db & 63) ^ swz64(r);
      gload_lds(A + (size_t)(bm + r) * NTOT + k0 + (cb >> 1), (char*)&As[bi][0][0] + lb);
      gload_lds(B + (size_t)(bn + r) * NTOT + k0 + (cb >> 1), (char*)&Bs[bi][0][0] + lb);
    }
  };

  floatx4 acc[4][4] = {};
  stage(0, 0);
  asm volatile("s_waitcnt vmcnt(0)" ::: "memory");
  __builtin_amdgcn_s_barrier();
  for (int t = 0; t < 32; ++t) {
    if (t < 31) stage(t + 1, (t + 1) & 1);
    const int bi = t & 1;
    const char* Ab = (const char*)&As[bi][0][0];
    const char* Bb = (const char*)&Bs[bi][0][0];
    short8 af[4], bfr[4];
    #pragma unroll
    for (int m = 0; m < 4; ++m) {
      const int row = wr + m * 16 + lr;
      af[m] = *reinterpret_cast<const short8*>(Ab + row * 64 + ((g * 16) ^ swz64(row)));
    }
    #pragma unroll
    for (int n = 0; n < 4; ++n) {
      const int row = wc + n * 16 + lr;
      bfr[n] = *reinterpret_cast<const short8*>(Bb + row * 64 + ((g * 16) ^ swz64(row)));
    }
    mm4x4(af, bfr, acc);
    asm volatile("s_waitcnt vmcnt(0)" ::: "memory");
    __builtin_amdgcn_s_barrier();
  }
  #pragma unroll
  for (int m = 0; m < 4; ++m) {
    const int row = bm + wr + m * 16 + g * 4;
    #pragma unroll
    for (int n = 0; n < 4; ++n) {
      const int col = bn + wc + n * 16 + lr;
      #pragma unroll
      for (int r = 0; r < 4; ++r)
        C[(size_t)(row + r) * CH + col] = acc[m][n][r];
    }
  }
}

// Q = (sum of 4 split-K partials) / dn -> bf16. Block per row; both dirs via z.
__global__ __launch_bounds__(256) void reduce_q_k(const float* __restrict__ Qp,
                                                  const float* __restrict__ dnp,
                                                  u16* __restrict__ Qb) {
  const int dir = blockIdx.z;
  Qp += (size_t)dir * 4 * NTOT * CH;
  dnp += (size_t)dir * NTOT * 64;
  Qb += (size_t)dir * NTOT * CH;
  const int row = blockIdx.x, tid = threadIdx.x;
  __shared__ float sdn;
  if (tid < 64) {
    float s = dnp[(size_t)row * 64 + tid];
    s = wave_sum64(s);
    if (tid == 0) sdn = 1.0f / s;
  }
  __syncthreads();
  const float rdn = sdn;
  const size_t o = (size_t)row * CH + tid;
  const size_t st = (size_t)NTOT * CH;
  const float q = (Qp[o] + Qp[o + st] + Qp[o + 2 * st] + Qp[o + 3 * st]) * rdn;
  Qb[o] = f2bf(q);
}

// ---------------------------------------------------------------------------
// Phase-2 flash: T-tile = Qb . X^T (never materialized); w = exp((2T-nx)*SCALE);
// s0, s1 = sum w*(idx-c), s2 = sum w*(idx-c)^2 per row. Both dirs. ONE 128x128
// j-tile per block (stats folded once after K-loop -> VGPR fits 4 blocks/CU).
// BK=32 double-buffered, swizzled staging.
__global__ __launch_bounds__(256, 4) void flash_stats_k(const u16* __restrict__ Qball,
                                                        const u16* __restrict__ abf,
                                                        const u16* __restrict__ bbf,
                                                        const float* __restrict__ na,
                                                        const float* __restrict__ nb,
                                                        const float* __restrict__ idxa,
                                                        const float* __restrict__ idxb,
                                                        float4* __restrict__ statsp) {
  const int dir = blockIdx.z;
  const u16* __restrict__ Qb = Qball + (size_t)dir * NTOT * CH;
  const u16* __restrict__ X = dir ? bbf : abf;
  const float* __restrict__ nx = dir ? nb : na;
  const float* __restrict__ idx = dir ? idxb : idxa;
  statsp += (size_t)dir * NTOT * 64;

  __shared__ u16 As[2][128][32];
  __shared__ u16 Bs[2][128][32];
  const int tid = threadIdx.x, wid = tid >> 6, lane = tid & 63;
  const int bm = blockIdx.y * 128;
  const int bn = blockIdx.x * 128;
  const int wr = (wid >> 1) * 64, wc = (wid & 1) * 64;
  const int lr = lane & 15, g = lane >> 4;

  auto stage = [&](int t, int bi) {
    const int k0 = t * 32;
    #pragma unroll
    for (int i = 0; i < 2; ++i) {
      const int lb = (wid + 4 * i) * 1024;
      const int db = lb + lane * 16;
      const int r = db >> 6;
      const int cb = (db & 63) ^ swz64(r);
      gload_lds(Qb + (size_t)(bm + r) * CH + k0 + (cb >> 1), (char*)&As[bi][0][0] + lb);
      gload_lds(X + (size_t)(bn + r) * CH + k0 + (cb >> 1), (char*)&Bs[bi][0][0] + lb);
    }
  };

  floatx4 acc[4][4] = {};
  stage(0, 0);
  asm volatile("s_waitcnt vmcnt(0)" ::: "memory");
  __builtin_amdgcn_s_barrier();
  #pragma unroll
  for (int t = 0; t < 8; ++t) {
    if (t < 7) stage(t + 1, (t + 1) & 1);
    const int bi = t & 1;
    const char* Ab = (const char*)&As[bi][0][0];
    const char* Bb = (const char*)&Bs[bi][0][0];
    short8 af[4], bfr[4];
    #pragma unroll
    for (int m = 0; m < 4; ++m) {
      const int row = wr + m * 16 + lr;
      af[m] = *reinterpret_cast<const short8*>(Ab + row * 64 + ((g * 16) ^ swz64(row)));
    }
    #pragma unroll
    for (int n = 0; n < 4; ++n) {
      const int row = wc + n * 16 + lr;
      bfr[n] = *reinterpret_cast<const short8*>(Bb + row * 64 + ((g * 16) ^ swz64(row)));
    }
    mm4x4(af, bfr, acc);
    if (t < 7) {
      asm volatile("s_waitcnt vmcnt(0)" ::: "memory");
      __builtin_amdgcn_s_barrier();
    }
  }
  // fold stats once (T never written). cen = idx[row] centering.
  float cen[4][4];
  #pragma unroll
  for (int m = 0; m < 4; ++m) {
    const int rowb = bm + wr + m * 16 + g * 4;
    #pragma unroll
    for (int r = 0; r < 4; ++r) cen[m][r] = idx[rowb + r];
  }
  float s0[4][4] = {}, s1[4][4] = {}, s2[4][4] = {};
  #pragma unroll
  for (int n = 0; n < 4; ++n) {
    const int col = bn + wc + n * 16 + lr;
    const float nxv = nx[col];
    const float iv = idx[col];
    #pragma unroll
    for (int m = 0; m < 4; ++m) {
      #pragma unroll
      for (int r = 0; r < 4; ++r) {
        const float w = __expf((2.f * acc[m][n][r] - nxv) * SCALE);
        const float d = iv - cen[m][r];
        s0[m][r] += w;
        s1[m][r] += w * d;
        s2[m][r] += w * d * d;
      }
    }
  }
  #pragma unroll
  for (int m = 0; m < 4; ++m) {
    const int rowb = bm + wr + m * 16 + g * 4;
    #pragma unroll
    for (int r = 0; r < 4; ++r) {
      float a = s0[m][r], b = s1[m][r], c = s2[m][r];
      #pragma unroll
      for (int o = 1; o < 16; o <<= 1) {
        a += __shfl_xor(a, o, 64);
        b += __shfl_xor(b, o, 64);
        c += __shfl_xor(c, o, 64);
      }
      if (lr == 0)
        statsp[(size_t)(rowb + r) * 64 + blockIdx.x * 2 + (wid & 1)] = make_float4(a, b, c, 0.f);
    }
  }
}

// per-row: combine 64 partials -> loss term. mu = S1/S0; var = S2/S0 - mu^2.
__global__ __launch_bounds__(256) void stats_combine_k(const float4* __restrict__ statsp,
                                                       float* __restrict__ terms) {
  const int row = blockIdx.x * 256 + threadIdx.x;   // 0..2*NTOT-1
  float S0 = 0.f, S1 = 0.f, S2 = 0.f;
  #pragma unroll
  for (int p = 0; p < 64; ++p) {
    const float4 v = statsp[(size_t)row * 64 + p];
    S0 += v.x; S1 += v.y; S2 += v.z;
  }
  const float mu = S1 / S0;
  const float var = S2 / S0 - mu * mu;
  terms[row] = mu * mu / var + LAM * logf(var);
}

__global__ __launch_bounds__(256) void final_reduce_k(const float* __restrict__ terms,
                                                      float* __restrict__ out) {
  float s = 0.f;
  for (int i = threadIdx.x; i < 2 * NTOT; i += 256) s += terms[i];
  __shared__ float red[4];
  s = wave_sum64(s);
  if ((threadIdx.x & 63) == 0) red[threadIdx.x >> 6] = s;
  __syncthreads();
  if (threadIdx.x == 0) out[0] = (red[0] + red[1] + red[2] + red[3]) * (1.0f / (2.0f * NTOT));
}

extern "C" void kernel_launch(void* const* d_in, const int* in_sizes, int n_in,
                              void* d_out, int out_size, void* d_ws, size_t ws_size,
                              hipStream_t stream) {
  const float* a    = (const float*)d_in[0];
  const float* b    = (const float*)d_in[1];
  const float* idxa = (const float*)d_in[2];
  const float* idxb = (const float*)d_in[3];
  float* out = (float*)d_out;
  char* ws = (char*)d_ws;

  size_t off = 0;
  u16*    E    = (u16*)(ws + off);    off += 2 * (size_t)NTOT * NTOT * 2;   // 64 MB
  float*  Qp   = (float*)(ws + off);  off += 2 * 4 * (size_t)NTOT * CH * 4; // 32 MB
  u16*    Qb   = (u16*)(ws + off);    off += 2 * (size_t)NTOT * CH * 2;     // 4 MB
  u16*    abf  = (u16*)(ws + off);    off += (size_t)NTOT * CH * 2;
  u16*    bbf  = (u16*)(ws + off);    off += (size_t)NTOT * CH * 2;
  u16*    att  = (u16*)(ws + off);    off += (size_t)NTOT * CH * 2;
  u16*    btt  = (u16*)(ws + off);    off += (size_t)NTOT * CH * 2;
  float*  na   = (float*)(ws + off);  off += (size_t)NTOT * 4;
  float*  nb   = (float*)(ws + off);  off += (size_t)NTOT * 4;
  float*  dnp  = (float*)(ws + off);  off += 2 * (size_t)NTOT * 64 * 4;     // 2 MB
  float4* stp  = (float4*)(ws + off); off += 2 * (size_t)NTOT * 64 * 16;    // 8 MB
  float*  terms = (float*)(ws + off);

  cvt_norm_k<<<2 * NTOT, 64, 0, stream>>>(a, b, abf, bbf, na, nb);
  transpose2_k<<<dim3(CH / 32, NTOT / 32, 2), 256, 0, stream>>>(abf, bbf, att, btt);
  gemm_exp_k<<<dim3(NTOT / 128, NTOT / 128, 2), 256, 0, stream>>>(abf, bbf, na, nb, E, dnp);
  gemm_qp_k<<<dim3(CH / 128, NTOT / 128, 8), 256, 0, stream>>>(E, att, btt, Qp);
  reduce_q_k<<<dim3(NTOT, 1, 2), 256, 0, stream>>>(Qp, dnp, Qb);
  flash_stats_k<<<dim3(NTOT / 128, NTOT / 128, 2), 256, 0, stream>>>(Qb, abf, bbf, na, nb,
                                                                     idxa, idxb, stp);
  stats_combine_k<<<2 * NTOT / 256, 256, 0, stream>>>(stp, terms);
  final_reduce_k<<<1, 256, 0, stream>>>(terms, out);
}

// Round 9
// 149.481 us; speedup vs baseline: 1.2649x; 1.0227x over previous
//
#include <hip/hip_runtime.h>

#define NTOT 4096
#define CH 256
#define SCALE 0.0390625f   // 1/(256*0.1)
#define LAM 0.001f

typedef unsigned short u16;
typedef __attribute__((ext_vector_type(8))) short short8;   // 8 bf16 (4 VGPRs)
typedef __attribute__((ext_vector_type(4))) float floatx4;  // MFMA acc

__device__ __forceinline__ float wave_sum64(float v) {
  #pragma unroll
  for (int o = 32; o; o >>= 1) v += __shfl_down(v, o, 64);
  return v;
}
__device__ __forceinline__ u16 f2bf(float f) {  // round-to-nearest-even
  unsigned u = __float_as_uint(f);
  u += 0x7fffu + ((u >> 16) & 1u);
  return (u16)(u >> 16);
}
__device__ __forceinline__ float bf2f(u16 h) {
  return __uint_as_float(((unsigned)h) << 16);
}
__device__ __forceinline__ void gload_lds(const u16* g, void* l) {
  __builtin_amdgcn_global_load_lds((const __attribute__((address_space(1))) void*)g,
                                   (__attribute__((address_space(3))) void*)l, 16, 0, 0);
}
__device__ __forceinline__ void mm4x4(const short8 (&av)[4], const short8 (&bv)[4],
                                      floatx4 (&acc)[4][4]) {
  #pragma unroll
  for (int m = 0; m < 4; ++m)
    #pragma unroll
    for (int n = 0; n < 4; ++n)
      acc[m][n] = __builtin_amdgcn_mfma_f32_16x16x32_bf16(av[m], bv[n], acc[m][n], 0, 0, 0);
}
// BK=32 tiles: rows are 64 B. Swizzle byte ^= ((row>>1)&3)<<4 -> 2-way aliasing
// (free). Applied on SOURCE + READ (rule #21; verified rounds 6-8).
__device__ __forceinline__ int swz64(int row) { return ((row >> 1) & 3) << 4; }

// Counted-vmcnt helpers (immediate must be literal)
#define WAIT_VM4() asm volatile("s_waitcnt vmcnt(4)" ::: "memory")
#define WAIT_VM0() asm volatile("s_waitcnt vmcnt(0)" ::: "memory")

// f32 -> bf16 for both inputs + row norms of the ROUNDED values (one wave/row).
__global__ __launch_bounds__(64) void cvt_norm_k(const float* __restrict__ a,
                                                 const float* __restrict__ b,
                                                 u16* __restrict__ ab, u16* __restrict__ bb,
                                                 float* __restrict__ na, float* __restrict__ nb) {
  int row = blockIdx.x;
  const float* src; u16* dst; float* nd;
  if (row < NTOT) { src = a; dst = ab; nd = na; }
  else { row -= NTOT; src = b; dst = bb; nd = nb; }
  const float4 v = *reinterpret_cast<const float4*>(src + (size_t)row * CH + threadIdx.x * 4);
  const u16 h0 = f2bf(v.x), h1 = f2bf(v.y), h2 = f2bf(v.z), h3 = f2bf(v.w);
  uint2 st;
  st.x = (unsigned)h0 | ((unsigned)h1 << 16);
  st.y = (unsigned)h2 | ((unsigned)h3 << 16);
  *reinterpret_cast<uint2*>(dst + (size_t)row * CH + threadIdx.x * 4) = st;
  const float f0 = bf2f(h0), f1 = bf2f(h1), f2 = bf2f(h2), f3 = bf2f(h3);
  float s = f0 * f0 + f1 * f1 + f2 * f2 + f3 * f3;
  s = wave_sum64(s);
  if (threadIdx.x == 0) nd[row] = s;
}

// [4096][256] -> [256][4096] bf16 transpose for both inputs (z selects a/b)
__global__ __launch_bounds__(256) void transpose2_k(const u16* __restrict__ ab,
                                                    const u16* __restrict__ bb,
                                                    u16* __restrict__ at, u16* __restrict__ bt) {
  const u16* __restrict__ src = blockIdx.z ? bb : ab;
  u16* __restrict__ dst = blockIdx.z ? bt : at;
  __shared__ u16 t[32][33];
  const int bx = blockIdx.x * 32, by = blockIdx.y * 32;
  const int lx = threadIdx.x & 31, ly = threadIdx.x >> 5;
  #pragma unroll
  for (int i = 0; i < 32; i += 8)
    t[ly + i][lx] = src[(size_t)(by + ly + i) * CH + bx + lx];
  __syncthreads();
  #pragma unroll
  for (int i = 0; i < 32; i += 8)
    dst[(size_t)(bx + ly + i) * NTOT + by + lx] = t[lx][ly + i];
}

// ---------------------------------------------------------------------------
// Phase-1 GEMM fused with exp: E = bf16(exp((2*X.Y^T - ny)*SCALE)), per-row
// partial sums dnp. Both dirs via blockIdx.z. BK=32, TRIPLE-buffered LDS
// (48 KB -> 3 blocks/CU), counted vmcnt(4), ONE barrier per K-step.
__global__ __launch_bounds__(256, 3) void gemm_exp_k(const u16* __restrict__ abf,
                                                     const u16* __restrict__ bbf,
                                                     const float* __restrict__ na,
                                                     const float* __restrict__ nb,
                                                     u16* __restrict__ E,
                                                     float* __restrict__ dnp) {
  const int dir = blockIdx.z;
  const u16* __restrict__ A = dir ? bbf : abf;
  const u16* __restrict__ B = dir ? abf : bbf;
  const float* __restrict__ ny = dir ? na : nb;
  E += (size_t)dir * NTOT * NTOT;
  dnp += (size_t)dir * NTOT * 64;

  __shared__ u16 As[3][128][32];
  __shared__ u16 Bs[3][128][32];
  const int tid = threadIdx.x, wid = tid >> 6, lane = tid & 63;
  const int bn = blockIdx.x * 128, bm = blockIdx.y * 128;
  const int wr = (wid >> 1) * 64, wc = (wid & 1) * 64;
  const int lr = lane & 15, g = lane >> 4;

  auto stage = [&](int t, int bi) {   // 4 gload_lds per wave
    const int k0 = t * 32;
    #pragma unroll
    for (int i = 0; i < 2; ++i) {
      const int lb = (wid + 4 * i) * 1024;
      const int db = lb + lane * 16;
      const int r = db >> 6;
      const int cb = (db & 63) ^ swz64(r);
      gload_lds(A + (size_t)(bm + r) * CH + k0 + (cb >> 1), (char*)&As[bi][0][0] + lb);
      gload_lds(B + (size_t)(bn + r) * CH + k0 + (cb >> 1), (char*)&Bs[bi][0][0] + lb);
    }
  };
  floatx4 acc[4][4] = {};
  auto compute = [&](int bi) {
    const char* Ab = (const char*)&As[bi][0][0];
    const char* Bb = (const char*)&Bs[bi][0][0];
    short8 af[4], bfr[4];
    #pragma unroll
    for (int m = 0; m < 4; ++m) {
      const int row = wr + m * 16 + lr;
      af[m] = *reinterpret_cast<const short8*>(Ab + row * 64 + ((g * 16) ^ swz64(row)));
    }
    #pragma unroll
    for (int n = 0; n < 4; ++n) {
      const int row = wc + n * 16 + lr;
      bfr[n] = *reinterpret_cast<const short8*>(Bb + row * 64 + ((g * 16) ^ swz64(row)));
    }
    mm4x4(af, bfr, acc);
  };

  stage(0, 0); stage(1, 1);
  #pragma unroll
  for (int t = 0; t < 8; ++t) {
    if (t < 7) { WAIT_VM4(); } else { WAIT_VM0(); }
    __builtin_amdgcn_s_barrier();
    if (t + 2 < 8) stage(t + 2, (t + 2) % 3);
    compute(t % 3);
  }
  // epilogue: w = exp(logit), write bf16 E, accumulate per-row sums
  float nyv[4];
  #pragma unroll
  for (int n = 0; n < 4; ++n) nyv[n] = ny[bn + wc + n * 16 + lr];
  float rowsum[4][4] = {};
  #pragma unroll
  for (int m = 0; m < 4; ++m) {
    const int rowb = bm + wr + m * 16 + g * 4;
    #pragma unroll
    for (int n = 0; n < 4; ++n) {
      const int col = bn + wc + n * 16 + lr;
      #pragma unroll
      for (int r = 0; r < 4; ++r) {
        const float w = __expf((2.f * acc[m][n][r] - nyv[n]) * SCALE);
        E[(size_t)(rowb + r) * NTOT + col] = f2bf(w);
        rowsum[m][r] += w;
      }
    }
  }
  #pragma unroll
  for (int m = 0; m < 4; ++m) {
    const int rowb = bm + wr + m * 16 + g * 4;
    #pragma unroll
    for (int r = 0; r < 4; ++r) {
      float s = rowsum[m][r];
      #pragma unroll
      for (int o = 1; o < 16; o <<= 1) s += __shfl_xor(s, o, 64);
      if (lr == 0) dnp[(size_t)(rowb + r) * 64 + blockIdx.x * 2 + (wid & 1)] = s;
    }
  }
}

// ---------------------------------------------------------------------------
// Qp = E . Yt^T, split-K 4, both dirs. z = dir*4 + kz. BK=32 triple-buffered,
// counted vmcnt, one barrier/step.
__global__ __launch_bounds__(256, 3) void gemm_qp_k(const u16* __restrict__ E,
                                                    const u16* __restrict__ att,
                                                    const u16* __restrict__ btt,
                                                    float* __restrict__ Qp) {
  const int dir = blockIdx.z >> 2, kz = blockIdx.z & 3;
  const u16* __restrict__ A = E + (size_t)dir * NTOT * NTOT;
  const u16* __restrict__ B = dir ? att : btt;
  float* __restrict__ C = Qp + (size_t)dir * 4 * NTOT * CH + (size_t)kz * NTOT * CH;
  const int k0base = kz * (NTOT / 4);

  __shared__ u16 As[3][128][32];
  __shared__ u16 Bs[3][128][32];
  const int tid = threadIdx.x, wid = tid >> 6, lane = tid & 63;
  const int bn = blockIdx.x * 128, bm = blockIdx.y * 128;
  const int wr = (wid >> 1) * 64, wc = (wid & 1) * 64;
  const int lr = lane & 15, g = lane >> 4;

  auto stage = [&](int t, int bi) {
    const int k0 = k0base + t * 32;
    #pragma unroll
    for (int i = 0; i < 2; ++i) {
      const int lb = (wid + 4 * i) * 1024;
      const int db = lb + lane * 16;
      const int r = db >> 6;
      const int cb = (db & 63) ^ swz64(r);
      gload_lds(A + (size_t)(bm + r) * NTOT + k0 + (cb >> 1), (char*)&As[bi][0][0] + lb);
      gload_lds(B + (size_t)(bn + r) * NTOT + k0 + (cb >> 1), (char*)&Bs[bi][0][0] + lb);
    }
  };
  floatx4 acc[4][4] = {};
  auto compute = [&](int bi) {
    const char* Ab = (const char*)&As[bi][0][0];
    const char* Bb = (const char*)&Bs[bi][0][0];
    short8 af[4], bfr[4];
    #pragma unroll
    for (int m = 0; m < 4; ++m) {
      const int row = wr + m * 16 + lr;
      af[m] = *reinterpret_cast<const short8*>(Ab + row * 64 + ((g * 16) ^ swz64(row)));
    }
    #pragma unroll
    for (int n = 0; n < 4; ++n) {
      const int row = wc + n * 16 + lr;
      bfr[n] = *reinterpret_cast<const short8*>(Bb + row * 64 + ((g * 16) ^ swz64(row)));
    }
    mm4x4(af, bfr, acc);
  };

  stage(0, 0); stage(1, 1);
  int cur = 0, nxt = 2;
  for (int t = 0; t < 32; ++t) {
    if (t < 31) { WAIT_VM4(); } else { WAIT_VM0(); }
    __builtin_amdgcn_s_barrier();
    if (t + 2 < 32) stage(t + 2, nxt);
    compute(cur);
    cur = cur == 2 ? 0 : cur + 1;
    nxt = nxt == 2 ? 0 : nxt + 1;
  }
  #pragma unroll
  for (int m = 0; m < 4; ++m) {
    const int row = bm + wr + m * 16 + g * 4;
    #pragma unroll
    for (int n = 0; n < 4; ++n) {
      const int col = bn + wc + n * 16 + lr;
      #pragma unroll
      for (int r = 0; r < 4; ++r)
        C[(size_t)(row + r) * CH + col] = acc[m][n][r];
    }
  }
}

// Q = (sum of 4 split-K partials) / dn -> bf16. Block per row; both dirs via z.
__global__ __launch_bounds__(256) void reduce_q_k(const float* __restrict__ Qp,
                                                  const float* __restrict__ dnp,
                                                  u16* __restrict__ Qb) {
  const int dir = blockIdx.z;
  Qp += (size_t)dir * 4 * NTOT * CH;
  dnp += (size_t)dir * NTOT * 64;
  Qb += (size_t)dir * NTOT * CH;
  const int row = blockIdx.x, tid = threadIdx.x;
  __shared__ float sdn;
  if (tid < 64) {
    float s = dnp[(size_t)row * 64 + tid];
    s = wave_sum64(s);
    if (tid == 0) sdn = 1.0f / s;
  }
  __syncthreads();
  const float rdn = sdn;
  const size_t o = (size_t)row * CH + tid;
  const size_t st = (size_t)NTOT * CH;
  const float q = (Qp[o] + Qp[o + st] + Qp[o + 2 * st] + Qp[o + 3 * st]) * rdn;
  Qb[o] = f2bf(q);
}

// ---------------------------------------------------------------------------
// Phase-2 flash: T-tile = Qb . X^T (never materialized); w = exp((2T-nx)*SCALE);
// s0, s1 = sum w*(idx-c), s2 = sum w*(idx-c)^2 per row. Both dirs. One 128x128
// j-tile per block. BK=32 triple-buffered, counted vmcnt, one barrier/step.
__global__ __launch_bounds__(256, 3) void flash_stats_k(const u16* __restrict__ Qball,
                                                        const u16* __restrict__ abf,
                                                        const u16* __restrict__ bbf,
                                                        const float* __restrict__ na,
                                                        const float* __restrict__ nb,
                                                        const float* __restrict__ idxa,
                                                        const float* __restrict__ idxb,
                                                        float4* __restrict__ statsp) {
  const int dir = blockIdx.z;
  const u16* __restrict__ Qb = Qball + (size_t)dir * NTOT * CH;
  const u16* __restrict__ X = dir ? bbf : abf;
  const float* __restrict__ nx = dir ? nb : na;
  const float* __restrict__ idx = dir ? idxb : idxa;
  statsp += (size_t)dir * NTOT * 64;

  __shared__ u16 As[3][128][32];
  __shared__ u16 Bs[3][128][32];
  const int tid = threadIdx.x, wid = tid >> 6, lane = tid & 63;
  const int bm = blockIdx.y * 128;
  const int bn = blockIdx.x * 128;
  const int wr = (wid >> 1) * 64, wc = (wid & 1) * 64;
  const int lr = lane & 15, g = lane >> 4;

  auto stage = [&](int t, int bi) {
    const int k0 = t * 32;
    #pragma unroll
    for (int i = 0; i < 2; ++i) {
      const int lb = (wid + 4 * i) * 1024;
      const int db = lb + lane * 16;
      const int r = db >> 6;
      const int cb = (db & 63) ^ swz64(r);
      gload_lds(Qb + (size_t)(bm + r) * CH + k0 + (cb >> 1), (char*)&As[bi][0][0] + lb);
      gload_lds(X + (size_t)(bn + r) * CH + k0 + (cb >> 1), (char*)&Bs[bi][0][0] + lb);
    }
  };
  floatx4 acc[4][4] = {};
  auto compute = [&](int bi) {
    const char* Ab = (const char*)&As[bi][0][0];
    const char* Bb = (const char*)&Bs[bi][0][0];
    short8 af[4], bfr[4];
    #pragma unroll
    for (int m = 0; m < 4; ++m) {
      const int row = wr + m * 16 + lr;
      af[m] = *reinterpret_cast<const short8*>(Ab + row * 64 + ((g * 16) ^ swz64(row)));
    }
    #pragma unroll
    for (int n = 0; n < 4; ++n) {
      const int row = wc + n * 16 + lr;
      bfr[n] = *reinterpret_cast<const short8*>(Bb + row * 64 + ((g * 16) ^ swz64(row)));
    }
    mm4x4(af, bfr, acc);
  };

  stage(0, 0); stage(1, 1);
  #pragma unroll
  for (int t = 0; t < 8; ++t) {
    if (t < 7) { WAIT_VM4(); } else { WAIT_VM0(); }
    __builtin_amdgcn_s_barrier();
    if (t + 2 < 8) stage(t + 2, (t + 2) % 3);
    compute(t % 3);
  }
  // fold stats once (T never written). cen = idx[row] centering.
  float cen[4][4];
  #pragma unroll
  for (int m = 0; m < 4; ++m) {
    const int rowb = bm + wr + m * 16 + g * 4;
    #pragma unroll
    for (int r = 0; r < 4; ++r) cen[m][r] = idx[rowb + r];
  }
  float s0[4][4] = {}, s1[4][4] = {}, s2[4][4] = {};
  #pragma unroll
  for (int n = 0; n < 4; ++n) {
    const int col = bn + wc + n * 16 + lr;
    const float nxv = nx[col];
    const float iv = idx[col];
    #pragma unroll
    for (int m = 0; m < 4; ++m) {
      #pragma unroll
      for (int r = 0; r < 4; ++r) {
        const float w = __expf((2.f * acc[m][n][r] - nxv) * SCALE);
        const float d = iv - cen[m][r];
        s0[m][r] += w;
        s1[m][r] += w * d;
        s2[m][r] += w * d * d;
      }
    }
  }
  #pragma unroll
  for (int m = 0; m < 4; ++m) {
    const int rowb = bm + wr + m * 16 + g * 4;
    #pragma unroll
    for (int r = 0; r < 4; ++r) {
      float a = s0[m][r], b = s1[m][r], c = s2[m][r];
      #pragma unroll
      for (int o = 1; o < 16; o <<= 1) {
        a += __shfl_xor(a, o, 64);
        b += __shfl_xor(b, o, 64);
        c += __shfl_xor(c, o, 64);
      }
      if (lr == 0)
        statsp[(size_t)(rowb + r) * 64 + blockIdx.x * 2 + (wid & 1)] = make_float4(a, b, c, 0.f);
    }
  }
}

// per-row: combine 64 partials -> loss term. mu = S1/S0; var = S2/S0 - mu^2.
__global__ __launch_bounds__(256) void stats_combine_k(const float4* __restrict__ statsp,
                                                       float* __restrict__ terms) {
  const int row = blockIdx.x * 256 + threadIdx.x;   // 0..2*NTOT-1
  float S0 = 0.f, S1 = 0.f, S2 = 0.f;
  #pragma unroll
  for (int p = 0; p < 64; ++p) {
    const float4 v = statsp[(size_t)row * 64 + p];
    S0 += v.x; S1 += v.y; S2 += v.z;
  }
  const float mu = S1 / S0;
  const float var = S2 / S0 - mu * mu;
  terms[row] = mu * mu / var + LAM * logf(var);
}

__global__ __launch_bounds__(256) void final_reduce_k(const float* __restrict__ terms,
                                                      float* __restrict__ out) {
  float s = 0.f;
  for (int i = threadIdx.x; i < 2 * NTOT; i += 256) s += terms[i];
  __shared__ float red[4];
  s = wave_sum64(s);
  if ((threadIdx.x & 63) == 0) red[threadIdx.x >> 6] = s;
  __syncthreads();
  if (threadIdx.x == 0) out[0] = (red[0] + red[1] + red[2] + red[3]) * (1.0f / (2.0f * NTOT));
}

extern "C" void kernel_launch(void* const* d_in, const int* in_sizes, int n_in,
                              void* d_out, int out_size, void* d_ws, size_t ws_size,
                              hipStream_t stream) {
  const float* a    = (const float*)d_in[0];
  const float* b    = (const float*)d_in[1];
  const float* idxa = (const float*)d_in[2];
  const float* idxb = (const float*)d_in[3];
  float* out = (float*)d_out;
  char* ws = (char*)d_ws;

  size_t off = 0;
  u16*    E    = (u16*)(ws + off);    off += 2 * (size_t)NTOT * NTOT * 2;   // 64 MB
  float*  Qp   = (float*)(ws + off);  off += 2 * 4 * (size_t)NTOT * CH * 4; // 32 MB
  u16*    Qb   = (u16*)(ws + off);    off += 2 * (size_t)NTOT * CH * 2;     // 4 MB
  u16*    abf  = (u16*)(ws + off);    off += (size_t)NTOT * CH * 2;
  u16*    bbf  = (u16*)(ws + off);    off += (size_t)NTOT * CH * 2;
  u16*    att  = (u16*)(ws + off);    off += (size_t)NTOT * CH * 2;
  u16*    btt  = (u16*)(ws + off);    off += (size_t)NTOT * CH * 2;
  float*  na   = (float*)(ws + off);  off += (size_t)NTOT * 4;
  float*  nb   = (float*)(ws + off);  off += (size_t)NTOT * 4;
  float*  dnp  = (float*)(ws + off);  off += 2 * (size_t)NTOT * 64 * 4;     // 2 MB
  float4* stp  = (float4*)(ws + off); off += 2 * (size_t)NTOT * 64 * 16;    // 8 MB
  float*  terms = (float*)(ws + off);

  cvt_norm_k<<<2 * NTOT, 64, 0, stream>>>(a, b, abf, bbf, na, nb);
  transpose2_k<<<dim3(CH / 32, NTOT / 32, 2), 256, 0, stream>>>(abf, bbf, att, btt);
  gemm_exp_k<<<dim3(NTOT / 128, NTOT / 128, 2), 256, 0, stream>>>(abf, bbf, na, nb, E, dnp);
  gemm_qp_k<<<dim3(CH / 128, NTOT / 128, 8), 256, 0, stream>>>(E, att, btt, Qp);
  reduce_q_k<<<dim3(NTOT, 1, 2), 256, 0, stream>>>(Qp, dnp, Qb);
  flash_stats_k<<<dim3(NTOT / 128, NTOT / 128, 2), 256, 0, stream>>>(Qb, abf, bbf, na, nb,
                                                                     idxa, idxb, stp);
  stats_combine_k<<<2 * NTOT / 256, 256, 0, stream>>>(stp, terms);
  final_reduce_k<<<1, 256, 0, stream>>>(terms, out);
}

// Round 10
// 135.882 us; speedup vs baseline: 1.3915x; 1.1001x over previous
//
#include <hip/hip_runtime.h>

#define NTOT 4096
#define CH 256
#define SCALE 0.0390625f   // 1/(256*0.1)
#define LAM 0.001f

typedef unsigned short u16;
typedef __attribute__((ext_vector_type(8))) short short8;   // 8 bf16 (4 VGPRs)
typedef __attribute__((ext_vector_type(4))) float floatx4;  // MFMA acc

__device__ __forceinline__ float wave_sum64(float v) {
  #pragma unroll
  for (int o = 32; o; o >>= 1) v += __shfl_down(v, o, 64);
  return v;
}
__device__ __forceinline__ u16 f2bf(float f) {  // round-to-nearest-even
  unsigned u = __float_as_uint(f);
  u += 0x7fffu + ((u >> 16) & 1u);
  return (u16)(u >> 16);
}
__device__ __forceinline__ float bf2f(u16 h) {
  return __uint_as_float(((unsigned)h) << 16);
}
__device__ __forceinline__ void gload_lds(const u16* g, void* l) {
  __builtin_amdgcn_global_load_lds((const __attribute__((address_space(1))) void*)g,
                                   (__attribute__((address_space(3))) void*)l, 16, 0, 0);
}
__device__ __forceinline__ void mm4x4(const short8 (&av)[4], const short8 (&bv)[4],
                                      floatx4 (&acc)[4][4]) {
  #pragma unroll
  for (int m = 0; m < 4; ++m)
    #pragma unroll
    for (int n = 0; n < 4; ++n)
      acc[m][n] = __builtin_amdgcn_mfma_f32_16x16x32_bf16(av[m], bv[n], acc[m][n], 0, 0, 0);
}

// f32 -> bf16 for both inputs + row norms of the ROUNDED values (one wave/row).
__global__ __launch_bounds__(64) void cvt_norm_k(const float* __restrict__ a,
                                                 const float* __restrict__ b,
                                                 u16* __restrict__ ab, u16* __restrict__ bb,
                                                 float* __restrict__ na, float* __restrict__ nb) {
  int row = blockIdx.x;
  const float* src; u16* dst; float* nd;
  if (row < NTOT) { src = a; dst = ab; nd = na; }
  else { row -= NTOT; src = b; dst = bb; nd = nb; }
  const float4 v = *reinterpret_cast<const float4*>(src + (size_t)row * CH + threadIdx.x * 4);
  const u16 h0 = f2bf(v.x), h1 = f2bf(v.y), h2 = f2bf(v.z), h3 = f2bf(v.w);
  uint2 st;
  st.x = (unsigned)h0 | ((unsigned)h1 << 16);
  st.y = (unsigned)h2 | ((unsigned)h3 << 16);
  *reinterpret_cast<uint2*>(dst + (size_t)row * CH + threadIdx.x * 4) = st;
  const float f0 = bf2f(h0), f1 = bf2f(h1), f2 = bf2f(h2), f3 = bf2f(h3);
  float s = f0 * f0 + f1 * f1 + f2 * f2 + f3 * f3;
  s = wave_sum64(s);
  if (threadIdx.x == 0) nd[row] = s;
}

// [4096][256] -> [256][4096] bf16 transpose for both inputs (z selects a/b)
__global__ __launch_bounds__(256) void transpose2_k(const u16* __restrict__ ab,
                                                    const u16* __restrict__ bb,
                                                    u16* __restrict__ at, u16* __restrict__ bt) {
  const u16* __restrict__ src = blockIdx.z ? bb : ab;
  u16* __restrict__ dst = blockIdx.z ? bt : at;
  __shared__ u16 t[32][33];
  const int bx = blockIdx.x * 32, by = blockIdx.y * 32;
  const int lx = threadIdx.x & 31, ly = threadIdx.x >> 5;
  #pragma unroll
  for (int i = 0; i < 32; i += 8)
    t[ly + i][lx] = src[(size_t)(by + ly + i) * CH + bx + lx];
  __syncthreads();
  #pragma unroll
  for (int i = 0; i < 32; i += 8)
    dst[(size_t)(bx + ly + i) * NTOT + by + lx] = t[lx][ly + i];
}

// ---------------------------------------------------------------------------
// Phase-1 GEMM fused with exp: E = bf16(exp((2*X.Y^T - ny)*SCALE)), per-row
// partial sums dnp. Round-6 compute structure (BK=64 dbuf, 128B-row XOR
// swizzle). XCD-AFFINITY remap: linear grid 2048; hardware maps wg->XCD wg%8;
// decode so each XCD owns 4 consecutive bm panels x ALL bn -> the whole B
// operand (4 MB) stays resident in that XCD's L2 (fill from L3 once per XCD,
// not once per block).
__global__ __launch_bounds__(256, 2) void gemm_exp_k(const u16* __restrict__ abf,
                                                     const u16* __restrict__ bbf,
                                                     const float* __restrict__ na,
                                                     const float* __restrict__ nb,
                                                     u16* __restrict__ E,
                                                     float* __restrict__ dnp) {
  const int wg = blockIdx.x;
  const int dir = wg >> 10;                 // 1024 blocks per dir
  const int w = wg & 1023;
  const int xcd = w & 7;
  const int local = w >> 3;                 // [0,128)
  const int bx = local & 31;                // bn index [0,32)
  const int by = xcd * 4 + (local >> 5);    // bm index: 4 consecutive per XCD

  const u16* __restrict__ A = dir ? bbf : abf;
  const u16* __restrict__ B = dir ? abf : bbf;
  const float* __restrict__ ny = dir ? na : nb;
  E += (size_t)dir * NTOT * NTOT;
  dnp += (size_t)dir * NTOT * 64;

  __shared__ u16 As[2][128][64];
  __shared__ u16 Bs[2][128][64];
  const int tid = threadIdx.x, wid = tid >> 6, lane = tid & 63;
  const int bn = bx * 128, bm = by * 128;
  const int wr = (wid >> 1) * 64, wc = (wid & 1) * 64;
  const int lr = lane & 15;

  auto stage = [&](int t, int bi) {
    const int k0 = t * 64;
    #pragma unroll
    for (int i = 0; i < 4; ++i) {
      const int lb = (wid + 4 * i) * 1024;          // wave-uniform LDS byte base
      const int db = lb + lane * 16;                // lane's linear dest byte
      const int r = db >> 7;                        // dest row (128 B rows)
      const int cb = (db & 127) ^ ((r & 7) << 4);   // inverse-swizzled source col
      gload_lds(A + (size_t)(bm + r) * CH + k0 + (cb >> 1), (char*)&As[bi][0][0] + lb);
      gload_lds(B + (size_t)(bn + r) * CH + k0 + (cb >> 1), (char*)&Bs[bi][0][0] + lb);
    }
  };

  floatx4 acc[4][4] = {};
  stage(0, 0);
  asm volatile("s_waitcnt vmcnt(0)" ::: "memory");
  __builtin_amdgcn_s_barrier();
  #pragma unroll
  for (int t = 0; t < 4; ++t) {
    if (t < 3) stage(t + 1, (t + 1) & 1);
    const int bi = t & 1;
    const char* Ab = (const char*)&As[bi][0][0];
    const char* Bb = (const char*)&Bs[bi][0][0];
    #pragma unroll
    for (int ks = 0; ks < 2; ++ks) {
      const int ob = ks * 64 + (lane >> 4) * 16;    // desired byte col in row
      short8 af[4], bfr[4];
      #pragma unroll
      for (int m = 0; m < 4; ++m) {
        const int row = wr + m * 16 + lr;
        af[m] = *reinterpret_cast<const short8*>(Ab + row * 128 + (ob ^ ((row & 7) << 4)));
      }
      #pragma unroll
      for (int n = 0; n < 4; ++n) {
        const int row = wc + n * 16 + lr;
        bfr[n] = *reinterpret_cast<const short8*>(Bb + row * 128 + (ob ^ ((row & 7) << 4)));
      }
      mm4x4(af, bfr, acc);
    }
    if (t < 3) {
      asm volatile("s_waitcnt vmcnt(0)" ::: "memory");
      __builtin_amdgcn_s_barrier();
    }
  }
  // epilogue: w = exp(logit), write bf16 E, accumulate per-row sums
  float nyv[4];
  #pragma unroll
  for (int n = 0; n < 4; ++n) nyv[n] = ny[bn + wc + n * 16 + lr];
  float rowsum[4][4] = {};
  #pragma unroll
  for (int m = 0; m < 4; ++m) {
    const int rowb = bm + wr + m * 16 + (lane >> 4) * 4;
    #pragma unroll
    for (int n = 0; n < 4; ++n) {
      const int col = bn + wc + n * 16 + lr;
      #pragma unroll
      for (int r = 0; r < 4; ++r) {
        const float w = __expf((2.f * acc[m][n][r] - nyv[n]) * SCALE);
        E[(size_t)(rowb + r) * NTOT + col] = f2bf(w);
        rowsum[m][r] += w;
      }
    }
  }
  #pragma unroll
  for (int m = 0; m < 4; ++m) {
    const int rowb = bm + wr + m * 16 + (lane >> 4) * 4;
    #pragma unroll
    for (int r = 0; r < 4; ++r) {
      float s = rowsum[m][r];
      #pragma unroll
      for (int o = 1; o < 16; o <<= 1) s += __shfl_xor(s, o, 64);
      if (lr == 0) dnp[(size_t)(rowb + r) * 64 + bx * 2 + (wid & 1)] = s;
    }
  }
}

// ---------------------------------------------------------------------------
// Qp = E . Yt^T, split-K 4, both dirs. Linear grid 512; dk = dir*4+kz pinned
// to XCD dk (wgid = j*8 + dk): B-slice (512 KB) L2-resident per XCD, E streams.
__global__ __launch_bounds__(256, 2) void gemm_qp_k(const u16* __restrict__ E,
                                                    const u16* __restrict__ att,
                                                    const u16* __restrict__ btt,
                                                    float* __restrict__ Qp) {
  const int wg = blockIdx.x;
  const int dk = wg & 7;                    // XCD id = dispatch wg%8
  const int j = wg >> 3;                    // [0,64)
  const int dir = dk >> 2, kz = dk & 3;
  const int bxi = j & 1, byi = j >> 1;      // bn [0,2), bm [0,32)

  const u16* __restrict__ A = E + (size_t)dir * NTOT * NTOT;
  const u16* __restrict__ B = dir ? att : btt;
  float* __restrict__ C = Qp + (size_t)dir * 4 * NTOT * CH + (size_t)kz * NTOT * CH;
  const int k0base = kz * (NTOT / 4);

  __shared__ u16 As[2][128][64];
  __shared__ u16 Bs[2][128][64];
  const int tid = threadIdx.x, wid = tid >> 6, lane = tid & 63;
  const int bn = bxi * 128, bm = byi * 128;
  const int wr = (wid >> 1) * 64, wc = (wid & 1) * 64;
  const int lr = lane & 15;

  auto stage = [&](int t, int bi) {
    const int k0 = k0base + t * 64;
    #pragma unroll
    for (int i = 0; i < 4; ++i) {
      const int lb = (wid + 4 * i) * 1024;
      const int db = lb + lane * 16;
      const int r = db >> 7;
      const int cb = (db & 127) ^ ((r & 7) << 4);
      gload_lds(A + (size_t)(bm + r) * NTOT + k0 + (cb >> 1), (char*)&As[bi][0][0] + lb);
      gload_lds(B + (size_t)(bn + r) * NTOT + k0 + (cb >> 1), (char*)&Bs[bi][0][0] + lb);
    }
  };

  floatx4 acc[4][4] = {};
  stage(0, 0);
  asm volatile("s_waitcnt vmcnt(0)" ::: "memory");
  __builtin_amdgcn_s_barrier();
  for (int t = 0; t < 16; ++t) {
    if (t < 15) stage(t + 1, (t + 1) & 1);
    const int bi = t & 1;
    const char* Ab = (const char*)&As[bi][0][0];
    const char* Bb = (const char*)&Bs[bi][0][0];
    #pragma unroll
    for (int ks = 0; ks < 2; ++ks) {
      const int ob = ks * 64 + (lane >> 4) * 16;
      short8 af[4], bfr[4];
      #pragma unroll
      for (int m = 0; m < 4; ++m) {
        const int row = wr + m * 16 + lr;
        af[m] = *reinterpret_cast<const short8*>(Ab + row * 128 + (ob ^ ((row & 7) << 4)));
      }
      #pragma unroll
      for (int n = 0; n < 4; ++n) {
        const int row = wc + n * 16 + lr;
        bfr[n] = *reinterpret_cast<const short8*>(Bb + row * 128 + (ob ^ ((row & 7) << 4)));
      }
      mm4x4(af, bfr, acc);
    }
    asm volatile("s_waitcnt vmcnt(0)" ::: "memory");
    __builtin_amdgcn_s_barrier();
  }
  #pragma unroll
  for (int m = 0; m < 4; ++m) {
    const int row = bm + wr + m * 16 + (lane >> 4) * 4;
    #pragma unroll
    for (int n = 0; n < 4; ++n) {
      const int col = bn + wc + n * 16 + lr;
      #pragma unroll
      for (int r = 0; r < 4; ++r)
        C[(size_t)(row + r) * CH + col] = acc[m][n][r];
    }
  }
}

// Q = (sum of 4 split-K partials) / dn -> bf16. Block per row; both dirs via z.
__global__ __launch_bounds__(256) void reduce_q_k(const float* __restrict__ Qp,
                                                  const float* __restrict__ dnp,
                                                  u16* __restrict__ Qb) {
  const int dir = blockIdx.z;
  Qp += (size_t)dir * 4 * NTOT * CH;
  dnp += (size_t)dir * NTOT * 64;
  Qb += (size_t)dir * NTOT * CH;
  const int row = blockIdx.x, tid = threadIdx.x;
  __shared__ float sdn;
  if (tid < 64) {
    float s = dnp[(size_t)row * 64 + tid];
    s = wave_sum64(s);
    if (tid == 0) sdn = 1.0f / s;
  }
  __syncthreads();
  const float rdn = sdn;
  const size_t o = (size_t)row * CH + tid;
  const size_t st = (size_t)NTOT * CH;
  const float q = (Qp[o] + Qp[o + st] + Qp[o + 2 * st] + Qp[o + 3 * st]) * rdn;
  Qb[o] = f2bf(q);
}

// ---------------------------------------------------------------------------
// Phase-2 flash: T-tile = Qb . X^T (never materialized); w = exp((2T-nx)*SCALE);
// s0, s1 = sum w*(idx-c), s2 = sum w*(idx-c)^2 per row. Round-6 structure
// (2 j-tiles x 4 K-steps, BK=64 dbuf). XCD-affinity: each XCD owns 4
// consecutive bm panels x all j-chunks -> X (4 MB) resident in its L2.
__global__ __launch_bounds__(256, 2) void flash_stats_k(const u16* __restrict__ Qball,
                                                        const u16* __restrict__ abf,
                                                        const u16* __restrict__ bbf,
                                                        const float* __restrict__ na,
                                                        const float* __restrict__ nb,
                                                        const float* __restrict__ idxa,
                                                        const float* __restrict__ idxb,
                                                        float4* __restrict__ statsp) {
  const int wg = blockIdx.x;
  const int dir = wg >> 9;                  // 512 blocks per dir
  const int w = wg & 511;
  const int xcd = w & 7;
  const int local = w >> 3;                 // [0,64)
  const int bx = local & 15;                // j-chunk [0,16)
  const int by = xcd * 4 + (local >> 4);    // bm [0,32): 4 consecutive per XCD

  const u16* __restrict__ Qb = Qball + (size_t)dir * NTOT * CH;
  const u16* __restrict__ X = dir ? bbf : abf;
  const float* __restrict__ nx = dir ? nb : na;
  const float* __restrict__ idx = dir ? idxb : idxa;
  statsp += (size_t)dir * NTOT * 32;

  __shared__ u16 As[2][128][64];
  __shared__ u16 Bs[2][128][64];
  const int tid = threadIdx.x, wid = tid >> 6, lane = tid & 63;
  const int bm = by * 128;
  const int jbase = bx * 256;
  const int wr = (wid >> 1) * 64, wc = (wid & 1) * 64;
  const int lr = lane & 15;

  auto stage = [&](int t, int bi) {
    const int k0 = (t & 3) * 64;
    const int bn = jbase + (t >> 2) * 128;
    #pragma unroll
    for (int i = 0; i < 4; ++i) {
      const int lb = (wid + 4 * i) * 1024;
      const int db = lb + lane * 16;
      const int r = db >> 7;
      const int cb = (db & 127) ^ ((r & 7) << 4);
      gload_lds(Qb + (size_t)(bm + r) * CH + k0 + (cb >> 1), (char*)&As[bi][0][0] + lb);
      gload_lds(X + (size_t)(bn + r) * CH + k0 + (cb >> 1), (char*)&Bs[bi][0][0] + lb);
    }
  };

  float cen[4][4];
  #pragma unroll
  for (int m = 0; m < 4; ++m) {
    const int rowb = bm + wr + m * 16 + (lane >> 4) * 4;
    #pragma unroll
    for (int r = 0; r < 4; ++r) cen[m][r] = idx[rowb + r];
  }
  float s0[4][4] = {}, s1[4][4] = {}, s2[4][4] = {};
  floatx4 acc[4][4] = {};

  stage(0, 0);
  asm volatile("s_waitcnt vmcnt(0)" ::: "memory");
  __builtin_amdgcn_s_barrier();
  #pragma unroll
  for (int t = 0; t < 8; ++t) {
    if (t < 7) stage(t + 1, (t + 1) & 1);
    const int bi = t & 1;
    const char* Ab = (const char*)&As[bi][0][0];
    const char* Bb = (const char*)&Bs[bi][0][0];
    #pragma unroll
    for (int ks = 0; ks < 2; ++ks) {
      const int ob = ks * 64 + (lane >> 4) * 16;
      short8 af[4], bfr[4];
      #pragma unroll
      for (int m = 0; m < 4; ++m) {
        const int row = wr + m * 16 + lr;
        af[m] = *reinterpret_cast<const short8*>(Ab + row * 128 + (ob ^ ((row & 7) << 4)));
      }
      #pragma unroll
      for (int n = 0; n < 4; ++n) {
        const int row = wc + n * 16 + lr;
        bfr[n] = *reinterpret_cast<const short8*>(Bb + row * 128 + (ob ^ ((row & 7) << 4)));
      }
      mm4x4(af, bfr, acc);
    }
    if ((t & 3) == 3) {  // end of a j-tile: fold stats, reset acc
      const int bn = jbase + (t >> 2) * 128;
      #pragma unroll
      for (int n = 0; n < 4; ++n) {
        const int col = bn + wc + n * 16 + lr;
        const float nxv = nx[col];
        const float iv = idx[col];
        #pragma unroll
        for (int m = 0; m < 4; ++m) {
          #pragma unroll
          for (int r = 0; r < 4; ++r) {
            const float w = __expf((2.f * acc[m][n][r] - nxv) * SCALE);
            const float d = iv - cen[m][r];
            s0[m][r] += w;
            s1[m][r] += w * d;
            s2[m][r] += w * d * d;
            acc[m][n][r] = 0.f;
          }
        }
      }
    }
    if (t < 7) {
      asm volatile("s_waitcnt vmcnt(0)" ::: "memory");
      __builtin_amdgcn_s_barrier();
    }
  }
  #pragma unroll
  for (int m = 0; m < 4; ++m) {
    const int rowb = bm + wr + m * 16 + (lane >> 4) * 4;
    #pragma unroll
    for (int r = 0; r < 4; ++r) {
      float a = s0[m][r], b = s1[m][r], c = s2[m][r];
      #pragma unroll
      for (int o = 1; o < 16; o <<= 1) {
        a += __shfl_xor(a, o, 64);
        b += __shfl_xor(b, o, 64);
        c += __shfl_xor(c, o, 64);
      }
      if (lr == 0)
        statsp[(size_t)(rowb + r) * 32 + bx * 2 + (wid & 1)] = make_float4(a, b, c, 0.f);
    }
  }
}

// per-row: combine 32 partials -> loss term. mu = S1/S0; var = S2/S0 - mu^2.
__global__ __launch_bounds__(256) void stats_combine_k(const float4* __restrict__ statsp,
                                                       float* __restrict__ terms) {
  const int row = blockIdx.x * 256 + threadIdx.x;   // 0..2*NTOT-1
  float S0 = 0.f, S1 = 0.f, S2 = 0.f;
  #pragma unroll
  for (int p = 0; p < 32; ++p) {
    const float4 v = statsp[(size_t)row * 32 + p];
    S0 += v.x; S1 += v.y; S2 += v.z;
  }
  const float mu = S1 / S0;
  const float var = S2 / S0 - mu * mu;
  terms[row] = mu * mu / var + LAM * logf(var);
}

__global__ __launch_bounds__(256) void final_reduce_k(const float* __restrict__ terms,
                                                      float* __restrict__ out) {
  float s = 0.f;
  for (int i = threadIdx.x; i < 2 * NTOT; i += 256) s += terms[i];
  __shared__ float red[4];
  s = wave_sum64(s);
  if ((threadIdx.x & 63) == 0) red[threadIdx.x >> 6] = s;
  __syncthreads();
  if (threadIdx.x == 0) out[0] = (red[0] + red[1] + red[2] + red[3]) * (1.0f / (2.0f * NTOT));
}

extern "C" void kernel_launch(void* const* d_in, const int* in_sizes, int n_in,
                              void* d_out, int out_size, void* d_ws, size_t ws_size,
                              hipStream_t stream) {
  const float* a    = (const float*)d_in[0];
  const float* b    = (const float*)d_in[1];
  const float* idxa = (const float*)d_in[2];
  const float* idxb = (const float*)d_in[3];
  float* out = (float*)d_out;
  char* ws = (char*)d_ws;

  size_t off = 0;
  u16*    E    = (u16*)(ws + off);    off += 2 * (size_t)NTOT * NTOT * 2;   // 64 MB
  float*  Qp   = (float*)(ws + off);  off += 2 * 4 * (size_t)NTOT * CH * 4; // 32 MB
  u16*    Qb   = (u16*)(ws + off);    off += 2 * (size_t)NTOT * CH * 2;     // 4 MB
  u16*    abf  = (u16*)(ws + off);    off += (size_t)NTOT * CH * 2;
  u16*    bbf  = (u16*)(ws + off);    off += (size_t)NTOT * CH * 2;
  u16*    att  = (u16*)(ws + off);    off += (size_t)NTOT * CH * 2;
  u16*    btt  = (u16*)(ws + off);    off += (size_t)NTOT * CH * 2;
  float*  na   = (float*)(ws + off);  off += (size_t)NTOT * 4;
  float*  nb   = (float*)(ws + off);  off += (size_t)NTOT * 4;
  float*  dnp  = (float*)(ws + off);  off += 2 * (size_t)NTOT * 64 * 4;     // 2 MB
  float4* stp  = (float4*)(ws + off); off += 2 * (size_t)NTOT * 32 * 16;    // 4 MB
  float*  terms = (float*)(ws + off);

  cvt_norm_k<<<2 * NTOT, 64, 0, stream>>>(a, b, abf, bbf, na, nb);
  transpose2_k<<<dim3(CH / 32, NTOT / 32, 2), 256, 0, stream>>>(abf, bbf, att, btt);
  gemm_exp_k<<<2048, 256, 0, stream>>>(abf, bbf, na, nb, E, dnp);
  gemm_qp_k<<<512, 256, 0, stream>>>(E, att, btt, Qp);
  reduce_q_k<<<dim3(NTOT, 1, 2), 256, 0, stream>>>(Qp, dnp, Qb);
  flash_stats_k<<<1024, 256, 0, stream>>>(Qb, abf, bbf, na, nb, idxa, idxb, stp);
  stats_combine_k<<<2 * NTOT / 256, 256, 0, stream>>>(stp, terms);
  final_reduce_k<<<1, 256, 0, stream>>>(terms, out);
}